// Round 1
// baseline (307.206 us; speedup 1.0000x reference)
//
#include <hip/hip_runtime.h>

// Problem constants (match reference)
#define ED    32      // embedding / hidden dim
#define SEQ_T 200     // history length
#define NB    4096    // batch
#define H3    96      // 3*ED
#define IV    100001
#define PV    100001
#define DV    1001
#define PV_MAX 100000 // PV-1

typedef __attribute__((ext_vector_type(8))) short bf16x8;   // 8 bf16 (4 VGPRs)
typedef __attribute__((ext_vector_type(4))) float f32x4;    // MFMA acc
typedef __attribute__((ext_vector_type(4))) int   i32x4;

#define LOG2E 1.44269504088896340736f

#if __has_builtin(__builtin_amdgcn_exp2f)
#define EXP2F(x) __builtin_amdgcn_exp2f(x)
#else
#define EXP2F(x) __expf((x) * 0.69314718055994530942f)
#endif

#define MFMA(a, b, c) __builtin_amdgcn_mfma_f32_16x16x32_bf16((a), (b), (c), 0, 0, 0)

__device__ __forceinline__ float rcp_fast(float x) { return __builtin_amdgcn_rcpf(x); }

// round-to-nearest-even fp32 -> bf16 (weights only; one-time cost)
__device__ __forceinline__ short bf16_rn(float v) {
  unsigned u = __float_as_uint(v);
  unsigned r = (u + 0x7fffu + ((u >> 16) & 1u)) >> 16;
  return (short)r;
}
__device__ __forceinline__ float bf16_f(short s) {
  return __uint_as_float(((unsigned)(unsigned short)s) << 16);
}

union I4B8 { i32x4 i; bf16x8 b; };

// Cheap split of 8 fp32 -> (hi, lo) bf16x8 fragments (truncate-hi; exact residual).
__device__ __forceinline__ void split_pack8(const f32x4 c0, const f32x4 c1,
                                            bf16x8& vh, bf16x8& vl) {
  float v[8] = {c0[0], c0[1], c0[2], c0[3], c1[0], c1[1], c1[2], c1[3]};
  float lo[8];
#pragma unroll
  for (int i = 0; i < 8; ++i) {
    const float hif = __uint_as_float(__float_as_uint(v[i]) & 0xffff0000u);
    lo[i] = v[i] - hif;
  }
  I4B8 H, L;
#pragma unroll
  for (int i = 0; i < 4; ++i) {
    H.i[i] = (int)__builtin_amdgcn_perm(__float_as_uint(v[2 * i + 1]),
                                        __float_as_uint(v[2 * i]), 0x07060302u);
    L.i[i] = (int)__builtin_amdgcn_perm(__float_as_uint(lo[2 * i + 1]),
                                        __float_as_uint(lo[2 * i]), 0x07060302u);
  }
  vh = H.b; vl = L.b;
}

template <int TOWER>
__device__ __forceinline__ void fetch_idx(const int* __restrict__ ids,
                                          const float* __restrict__ prices,
                                          const int* __restrict__ depts,
                                          int base, int t, float pmean, float prsq,
                                          int& idx, bool& mk) {
  if constexpr (TOWER == 0) {
    idx = ids[base + t];
    mk = true;
  } else if constexpr (TOWER == 1) {
    const float p = prices[base + t];
    const float pn = (p - pmean) * prsq;
    mk = (pn != 0.0f);
    int q = (int)pn;
    q = q < 0 ? 0 : (q > PV_MAX ? PV_MAX : q);
    idx = q;
  } else {
    const int d = depts[base + t];
    mk = (d != 0);
    idx = d;
  }
}

// ---------------------------------------------------------------------------
// Hidden-split GRU: TWO waves per 16-row batch chain. Wave tl owns gate tiles
// {tl, 2+tl, 4+tl} (hidden half tl*16..tl*16+15). Per step each wave does 18
// MFMAs + gates for 4 D-elems/lane (half of before), and the full 32-wide h
// B-fragment is exchanged through double-buffered, XOR-swizzled LDS with one
// raw s_barrier per step (lgkmcnt-only wait -> emb prefetch vmcnt stays in
// flight). Weights pre-scaled by log2e (z,r) / 2*log2e (h-gate) so gates use
// v_exp directly; biases feed the first MFMA as its C operand (no acc init).
// Numerics (trunc hi/lo split, 3-term MFMA products) match the previous
// passing kernel.
// ---------------------------------------------------------------------------
template <int TOWER>
__device__ __forceinline__ void tower_split(
    const int* __restrict__ ids, const float* __restrict__ prices,
    const int* __restrict__ depts, const float* __restrict__ emb,
    const float* __restrict__ Wx, const float* __restrict__ Wh,
    const float* __restrict__ Bb, float pmean, float prsq,
    float* __restrict__ out, short* hbuf) {
  const int tid  = threadIdx.x;
  const int tl   = tid >> 6;          // wave id == hidden half owned
  const int lane = tid & 63;
  const int l15  = lane & 15;
  const int quad = (lane >> 4) & 3;
  const int bRow = blockIdx.x * 16 + l15;
  const int base = bRow * SEQ_T;

  // Weights: 3 gate tiles (z,r,h) for this wave's hidden half; hi/lo split of
  // log2e-scaled weights. Natural k for BOTH Wx and Wh (h arrives via LDS in
  // natural k-order, so no k-permutation needed anymore).
  bf16x8 wxh[3], wxl[3], whh[3], whl[3];
#pragma unroll
  for (int g = 0; g < 3; ++g) {
    const float sc = (g == 2) ? (2.0f * LOG2E) : LOG2E;
    const int col = (g * 2 + tl) * 16 + l15;
#pragma unroll
    for (int j = 0; j < 8; ++j) {
      const int k = quad * 8 + j;
      float w = Wx[k * H3 + col] * sc;
      short hi = bf16_rn(w);
      wxh[g][j] = hi;
      wxl[g][j] = bf16_rn(w - bf16_f(hi));
      w = Wh[k * H3 + col] * sc;
      hi = bf16_rn(w);
      whh[g][j] = hi;
      whl[g][j] = bf16_rn(w - bf16_f(hi));
    }
  }

  // Bias vectors in D-layout (hidden = tl*16 + quad*4 + rg), pre-scaled.
  const int h4 = tl * 16 + quad * 4;
  const f32x4 cz  = (*(const f32x4*)(Bb + h4)       + *(const f32x4*)(Bb + 96 + h4))  * LOG2E;
  const f32x4 cr  = (*(const f32x4*)(Bb + 32 + h4)  + *(const f32x4*)(Bb + 128 + h4)) * LOG2E;
  const f32x4 bi2 = *(const f32x4*)(Bb + 64 + h4)  * (2.0f * LOG2E);
  const f32x4 bh2 = *(const f32x4*)(Bb + 160 + h4) * (2.0f * LOG2E);

  // LDS h-exchange: hbuf[buf(2)][l15(16)][G'(8)][8 shorts], 2048 shorts = 4 KB.
  // Granule G = plane*4 + kblock (plane 0=hi,1=lo; kblock = k>>3), swizzled
  // G' = G ^ (l15 & 7) so the 128 B row stride doesn't alias banks.
  // Writer (lane quad,l15): k = tl*16 + quad*4 + rg -> kblock tl*2+(quad>>1),
  // 4 shorts at in-granule offset (quad&1)*4 (one b64 per plane).
  // Reader: kblock = quad, 8 contiguous shorts (one b128 per plane).
  const int key = l15 & 7;
  const int qw  = tl * 2 + (quad >> 1);
  const int widx_hi = l15 * 64 + ((qw ^ key) * 8)        + (quad & 1) * 4;
  const int widx_lo = l15 * 64 + (((4 | qw) ^ key) * 8)  + (quad & 1) * 4;
  const int ridx_hh = l15 * 64 + ((quad ^ key) * 8);
  const int ridx_hl = l15 * 64 + (((4 | quad) ^ key) * 8);

  // Zero h(-1) in buf 0 (the two waves' write slots jointly cover the buffer).
  *(int2*)&hbuf[widx_hi] = make_int2(0, 0);
  *(int2*)&hbuf[widx_lo] = make_int2(0, 0);
  asm volatile("s_waitcnt lgkmcnt(0)" ::: "memory");
  __builtin_amdgcn_s_barrier();
  asm volatile("" ::: "memory");

  f32x4 hD = (f32x4)0.0f;

  // Depth-2 emb prefetch (steps are short now; 1 step may not cover L3 latency).
  int idx; bool mk0, mk1;
  fetch_idx<TOWER>(ids, prices, depts, base, 0, pmean, prsq, idx, mk0);
  f32x4 e0a = *(const f32x4*)(emb + (size_t)idx * ED + quad * 8);
  f32x4 e0b = *(const f32x4*)(emb + (size_t)idx * ED + quad * 8 + 4);
  fetch_idx<TOWER>(ids, prices, depts, base, 1, pmean, prsq, idx, mk1);
  f32x4 e1a = *(const f32x4*)(emb + (size_t)idx * ED + quad * 8);
  f32x4 e1b = *(const f32x4*)(emb + (size_t)idx * ED + quad * 8 + 4);

  for (int t = 0; t < SEQ_T; ++t) {
    const f32x4 c0 = e0a, c1 = e0b;
    const bool mk = mk0;
    e0a = e1a; e0b = e1b; mk0 = mk1;
    if (t + 2 < SEQ_T) {
      int idn;
      fetch_idx<TOWER>(ids, prices, depts, base, t + 2, pmean, prsq, idn, mk1);
      e1a = *(const f32x4*)(emb + (size_t)idn * ED + quad * 8);
      e1b = *(const f32x4*)(emb + (size_t)idn * ED + quad * 8 + 4);
    }

    // emb B-fragment (full K=32; both waves need it).
    bf16x8 ebh, ebl;
    split_pack8(c0, c1, ebh, ebl);

    // h(t-1) B-fragment from the exchange buffer.
    const int rbo = (t & 1) << 10;
    const bf16x8 hh = *(const bf16x8*)&hbuf[ridx_hh + rbo];
    const bf16x8 hl = *(const bf16x8*)&hbuf[ridx_hl + rbo];

    // 18 MFMAs: xp (independent of h) first, rec after the ds_reads land.
    // Bias vectors go in as the first MFMA's C operand (no init movs).
    f32x4 az  = MFMA(wxh[0], ebh, cz);
    az  = MFMA(wxh[0], ebl, az);
    az  = MFMA(wxl[0], ebh, az);
    f32x4 ar  = MFMA(wxh[1], ebh, cr);
    ar  = MFMA(wxh[1], ebl, ar);
    ar  = MFMA(wxl[1], ebh, ar);
    f32x4 axh = MFMA(wxh[2], ebh, bi2);
    axh = MFMA(wxh[2], ebl, axh);
    axh = MFMA(wxl[2], ebh, axh);
    f32x4 arh = MFMA(whh[2], hh, bh2);
    arh = MFMA(whh[2], hl, arh);
    arh = MFMA(whl[2], hh, arh);
    az  = MFMA(whh[0], hh, az);
    az  = MFMA(whh[0], hl, az);
    az  = MFMA(whl[0], hh, az);
    ar  = MFMA(whh[1], hh, ar);
    ar  = MFMA(whh[1], hl, ar);
    ar  = MFMA(whl[1], hh, ar);

    // Gates (batch = l15, hidden = tl*16 + quad*4 + rg). Accumulators are
    // pre-scaled by log2e (z,r) / 2*log2e (h-gate) -> exp2 directly.
#pragma unroll
    for (int rg = 0; rg < 4; ++rg) {
      const float z  = rcp_fast(1.0f + EXP2F(-az[rg]));
      const float r  = rcp_fast(1.0f + EXP2F(-ar[rg]));
      const float e  = EXP2F(-(axh[rg] + r * arh[rg]));
      const float g  = (1.0f - e) * rcp_fast(1.0f + e);
      const float hn = g + z * (hD[rg] - g);          // = z*h + (1-z)*g
      hD[rg] = mk ? hn : hD[rg];
    }

    // Split own 4 h values and publish for step t+1 (other buffer).
    {
      float lo[4];
#pragma unroll
      for (int i = 0; i < 4; ++i) {
        const float hif = __uint_as_float(__float_as_uint(hD[i]) & 0xffff0000u);
        lo[i] = hD[i] - hif;
      }
      const int d0  = (int)__builtin_amdgcn_perm(__float_as_uint(hD[1]), __float_as_uint(hD[0]), 0x07060302u);
      const int d1  = (int)__builtin_amdgcn_perm(__float_as_uint(hD[3]), __float_as_uint(hD[2]), 0x07060302u);
      const int l0_ = (int)__builtin_amdgcn_perm(__float_as_uint(lo[1]), __float_as_uint(lo[0]), 0x07060302u);
      const int l1_ = (int)__builtin_amdgcn_perm(__float_as_uint(lo[3]), __float_as_uint(lo[2]), 0x07060302u);
      const int wbo = ((t + 1) & 1) << 10;
      *(int2*)&hbuf[widx_hi + wbo] = make_int2(d0, d1);
      *(int2*)&hbuf[widx_lo + wbo] = make_int2(l0_, l1_);
    }

    // Raw barrier: drain LDS only (lgkmcnt). vmcnt (emb prefetch) stays live.
    asm volatile("s_waitcnt lgkmcnt(0)" ::: "memory");
    __builtin_amdgcn_s_barrier();
    asm volatile("" ::: "memory");
  }

#pragma unroll
  for (int dummy = 0; dummy < 1; ++dummy)
    *(f32x4*)(out + (size_t)bRow * H3 + TOWER * ED + tl * 16 + quad * 4) = hD;
}

__global__ void __launch_bounds__(128) gru_fused(
    const int* __restrict__ ids, const float* __restrict__ prices, const int* __restrict__ depts,
    const float* __restrict__ item_table, const float* __restrict__ price_table,
    const float* __restrict__ dept_table,
    const float* __restrict__ item_Wx, const float* __restrict__ item_Wh,
    const float* __restrict__ item_b,
    const float* __restrict__ price_Wx, const float* __restrict__ price_Wh,
    const float* __restrict__ price_b,
    const float* __restrict__ dept_Wx, const float* __restrict__ dept_Wh,
    const float* __restrict__ dept_b,
    const float* __restrict__ price_mean, const float* __restrict__ price_var,
    float* __restrict__ out) {
  __shared__ short hbuf[2048];   // 4 KB: [2 buf][16 batch][8 granules][8 shorts]
  const int tower = blockIdx.y;
  if (tower == 0) {
    tower_split<0>(ids, prices, depts, item_table, item_Wx, item_Wh, item_b,
                   0.0f, 0.0f, out, hbuf);
  } else if (tower == 1) {
    const float pm = price_mean[0];
    const float pr = rsqrtf(price_var[0]);
    tower_split<1>(ids, prices, depts, price_table, price_Wx, price_Wh, price_b,
                   pm, pr, out, hbuf);
  } else {
    tower_split<2>(ids, prices, depts, dept_table, dept_Wx, dept_Wh, dept_b,
                   0.0f, 0.0f, out, hbuf);
  }
}

extern "C" void kernel_launch(void* const* d_in, const int* in_sizes, int n_in,
                              void* d_out, int out_size, void* d_ws, size_t ws_size,
                              hipStream_t stream) {
  const int*   ids         = (const int*)d_in[0];
  const float* prices      = (const float*)d_in[1];
  const int*   depts       = (const int*)d_in[2];
  const float* item_table  = (const float*)d_in[3];
  const float* price_table = (const float*)d_in[4];
  const float* dept_table  = (const float*)d_in[5];
  const float* item_Wx     = (const float*)d_in[6];
  const float* item_Wh     = (const float*)d_in[7];
  const float* item_b      = (const float*)d_in[8];
  const float* price_Wx    = (const float*)d_in[9];
  const float* price_Wh    = (const float*)d_in[10];
  const float* price_b     = (const float*)d_in[11];
  const float* dept_Wx     = (const float*)d_in[12];
  const float* dept_Wh     = (const float*)d_in[13];
  const float* dept_b      = (const float*)d_in[14];
  const float* price_mean  = (const float*)d_in[15];
  const float* price_var   = (const float*)d_in[16];
  float* out = (float*)d_out;

  dim3 grid(NB / 16, 3, 1);   // 768 blocks x 2 waves = 1536 waves (6/CU)
  gru_fused<<<grid, 128, 0, stream>>>(
      ids, prices, depts, item_table, price_table, dept_table,
      item_Wx, item_Wh, item_b, price_Wx, price_Wh, price_b,
      dept_Wx, dept_Wh, dept_b, price_mean, price_var, out);
}

// Round 2
// 294.486 us; speedup vs baseline: 1.0432x; 1.0432x over previous
//
#include <hip/hip_runtime.h>

// Problem constants (match reference)
#define ED    32      // embedding / hidden dim
#define SEQ_T 200     // history length
#define NB    4096    // batch
#define H3    96      // 3*ED
#define PV_MAX 100000 // PV-1

typedef __attribute__((ext_vector_type(8))) short bf16x8;   // 8 bf16 (4 VGPRs)
typedef __attribute__((ext_vector_type(4))) float f32x4;    // MFMA acc
typedef __attribute__((ext_vector_type(4))) int   i32x4;

#define LOG2E 1.44269504088896340736f

#if __has_builtin(__builtin_amdgcn_exp2f)
#define EXP2F(x) __builtin_amdgcn_exp2f(x)
#else
#define EXP2F(x) __expf((x) * 0.69314718055994530942f)
#endif

#define MFMA(a, b, c) __builtin_amdgcn_mfma_f32_16x16x32_bf16((a), (b), (c), 0, 0, 0)

__device__ __forceinline__ float rcp_fast(float x) { return __builtin_amdgcn_rcpf(x); }

// round-to-nearest-even fp32 -> bf16 (weights only; one-time cost)
__device__ __forceinline__ short bf16_rn(float v) {
  unsigned u = __float_as_uint(v);
  unsigned r = (u + 0x7fffu + ((u >> 16) & 1u)) >> 16;
  return (short)r;
}
__device__ __forceinline__ float bf16_f(short s) {
  return __uint_as_float(((unsigned)(unsigned short)s) << 16);
}

union I4B8 { i32x4 i; bf16x8 b; };

// Cheap split of 8 fp32 -> (hi, lo) bf16x8 fragments (truncate-hi; exact residual).
__device__ __forceinline__ void split_pack8(const f32x4 c0, const f32x4 c1,
                                            bf16x8& vh, bf16x8& vl) {
  float v[8] = {c0[0], c0[1], c0[2], c0[3], c1[0], c1[1], c1[2], c1[3]};
  float lo[8];
#pragma unroll
  for (int i = 0; i < 8; ++i) {
    const float hif = __uint_as_float(__float_as_uint(v[i]) & 0xffff0000u);
    lo[i] = v[i] - hif;
  }
  I4B8 H, L;
#pragma unroll
  for (int i = 0; i < 4; ++i) {
    H.i[i] = (int)__builtin_amdgcn_perm(__float_as_uint(v[2 * i + 1]),
                                        __float_as_uint(v[2 * i]), 0x07060302u);
    L.i[i] = (int)__builtin_amdgcn_perm(__float_as_uint(lo[2 * i + 1]),
                                        __float_as_uint(lo[2 * i]), 0x07060302u);
  }
  vh = H.b; vl = L.b;
}

// ---------------------------------------------------------------------------
// Single-wave GRU (round-0 verified structure) + stall attacks:
//  * xp(t+1) software-pipelined: 18 independent MFMAs issued between the rec
//    chain and the gate transcendental tail of step t (rec chains now 3-deep).
//  * ids/prices/depts LDS-staged 16 steps at a time (coalesced int4 loads);
//    per-step id access = conflict-free ds_read_b32 broadcast, not a 16-line
//    global gather. Single-wave block -> no barrier, lgkmcnt only.
//  * price tower: normalized index is provably in {0,1}; both rows preloaded
//    as split fragments, per-step cndmask select (guarded fallback gather).
// Arithmetic identical to the verified kernel (trunc hi/lo split, 3-term
// MFMA, log2e-folded weights, bias-as-C).
// ---------------------------------------------------------------------------
template <int TOWER>
__device__ __forceinline__ void tower_fused(
    const int* __restrict__ ids, const float* __restrict__ prices,
    const int* __restrict__ depts, const float* __restrict__ emb,
    const float* __restrict__ Wx, const float* __restrict__ Wh,
    const float* __restrict__ Bb, float pmean, float prsq,
    float* __restrict__ out, int (*sid)[16][20]) {
  const int lane = threadIdx.x & 63;
  const int l15  = lane & 15;
  const int quad = lane >> 4;
  const int bRow = blockIdx.x * 16 + l15;

  // Wh A-fragments k-permuted (so hD is directly the B-fragment), Wx natural.
  // All weights pre-scaled by log2e (z,r tiles) / 2*log2e (h-gate tiles).
  bf16x8 wh_hi[6], wh_lo[6], wx_hi[6], wx_lo[6];
#pragma unroll
  for (int tile = 0; tile < 6; ++tile) {
    const float sc = (tile >= 4) ? (2.0f * LOG2E) : LOG2E;
#pragma unroll
    for (int j = 0; j < 8; ++j) {
      const int kperm = quad * 4 + (j & 3) + 16 * (j >> 2);
      float w = Wh[kperm * H3 + tile * 16 + l15] * sc;
      short hi = bf16_rn(w);
      wh_hi[tile][j] = hi;
      wh_lo[tile][j] = bf16_rn(w - bf16_f(hi));
      w = Wx[(quad * 8 + j) * H3 + tile * 16 + l15] * sc;
      hi = bf16_rn(w);
      wx_hi[tile][j] = hi;
      wx_lo[tile][j] = bf16_rn(w - bf16_f(hi));
    }
  }

  // Bias vectors in D-layout (hidden = tl*16 + quad*4 + rg), pre-scaled.
  f32x4 cz[2], cr[2], bi2[2], bh2[2];
#pragma unroll
  for (int tl = 0; tl < 2; ++tl) {
    const int h4 = tl * 16 + quad * 4;
    cz[tl]  = (*(const f32x4*)(Bb + h4)       + *(const f32x4*)(Bb + 96 + h4))  * LOG2E;
    cr[tl]  = (*(const f32x4*)(Bb + 32 + h4)  + *(const f32x4*)(Bb + 128 + h4)) * LOG2E;
    bi2[tl] = *(const f32x4*)(Bb + 64 + h4)  * (2.0f * LOG2E);
    bh2[tl] = *(const f32x4*)(Bb + 160 + h4) * (2.0f * LOG2E);
  }

  // ---- LDS staging of the per-row scalar stream (ids / prices / depts) ----
  const int srow = lane >> 2, scol = lane & 3;
  const int* sbase = (TOWER == 0) ? ids : (TOWER == 1 ? (const int*)prices : depts);
  const size_t srcoff = (size_t)(blockIdx.x * 16 + srow) * SEQ_T;
  auto stage = [&](int tb, int buf) {
    int tc = tb + scol * 4;
    if (tc > SEQ_T - 4) tc = SEQ_T - 4;               // clamp: stay in-bounds
    *(i32x4*)&sid[buf][srow][scol * 4] = *(const i32x4*)(sbase + srcoff + tc);
  };
  auto rd_id = [&](int t) -> int { return sid[(t >> 4) & 1][l15][t & 15]; };

  // Price tower: rows {0,1} preloaded as split fragments.
  bf16x8 p0h, p0l, p1h, p1l;
  if constexpr (TOWER == 1) {
    split_pack8(*(const f32x4*)(emb + quad * 8),
                *(const f32x4*)(emb + quad * 8 + 4), p0h, p0l);
    split_pack8(*(const f32x4*)(emb + ED + quad * 8),
                *(const f32x4*)(emb + ED + quad * 8 + 4), p1h, p1l);
  }
  auto price_frag = [&](int s, bf16x8& bh, bf16x8& bl) {
    const float p = __int_as_float(rd_id(s));
    const float pn = (p - pmean) * prsq;
    int q = (int)pn;
    q = q < 0 ? 0 : (q > PV_MAX ? PV_MAX : q);
    if (__builtin_expect(__any(q > 1), 0)) {          // data-safety fallback
      split_pack8(*(const f32x4*)(emb + (size_t)q * ED + quad * 8),
                  *(const f32x4*)(emb + (size_t)q * ED + quad * 8 + 4), bh, bl);
    } else {
      I4B8 a, b, A0, A1, B0, B1;
      A0.b = p0h; A1.b = p1h; B0.b = p0l; B1.b = p1l;
      const bool one = (q == 1);
#pragma unroll
      for (int i = 0; i < 4; ++i) {
        a.i[i] = one ? A1.i[i] : A0.i[i];
        b.i[i] = one ? B1.i[i] : B0.i[i];
      }
      bh = a.b; bl = b.b;
    }
  };
  auto pf = [&](int t, f32x4& a, f32x4& b) {          // item/dept emb gather
    const int idx = rd_id(t);
    const float* r = emb + (size_t)idx * ED + quad * 8;
    a = *(const f32x4*)r;
    b = *(const f32x4*)(r + 4);
  };
  auto get_mask = [&](int t) -> bool {
    if constexpr (TOWER == 0) return true;
    else if constexpr (TOWER == 1) {
      const float p = __int_as_float(rd_id(t));
      return (p - pmean) * prsq != 0.0f;
    } else return rd_id(t) != 0;
  };

  // ---- Prologue: stage chunk 0, build xp(0), prefetch e(1). ----
  stage(0, 0);
  asm volatile("s_waitcnt lgkmcnt(0)" ::: "memory");

  f32x4 hD[2];
  hD[0] = (f32x4)0.0f; hD[1] = (f32x4)0.0f;
  f32x4 eNa = (f32x4)0.0f, eNb = (f32x4)0.0f;         // emb(t+1) for item/dept
  bf16x8 e0h, e0l;
  if constexpr (TOWER == 1) {
    price_frag(0, e0h, e0l);
  } else {
    f32x4 a, b;
    pf(0, a, b);
    pf(1, eNa, eNb);
    split_pack8(a, b, e0h, e0l);
  }

  f32x4 xpA[6], xpB[6];
#pragma unroll
  for (int tl = 0; tl < 2; ++tl) {
    xpA[tl]     = MFMA(wx_hi[tl],     e0h, cz[tl]);
    xpA[tl]     = MFMA(wx_hi[tl],     e0l, xpA[tl]);
    xpA[tl]     = MFMA(wx_lo[tl],     e0h, xpA[tl]);
    xpA[2 + tl] = MFMA(wx_hi[2 + tl], e0h, cr[tl]);
    xpA[2 + tl] = MFMA(wx_hi[2 + tl], e0l, xpA[2 + tl]);
    xpA[2 + tl] = MFMA(wx_lo[2 + tl], e0h, xpA[2 + tl]);
    xpA[4 + tl] = MFMA(wx_hi[4 + tl], e0h, bi2[tl]);
    xpA[4 + tl] = MFMA(wx_hi[4 + tl], e0l, xpA[4 + tl]);
    xpA[4 + tl] = MFMA(wx_lo[4 + tl], e0h, xpA[4 + tl]);
  }

  // ---- Steady-state step. xpC = bias+Wx*e(t) (ready); builds xpN for t+1. ----
  auto step = [&](int t, f32x4 (&xpC)[6], f32x4 (&xpN)[6]) {
    // 1. split h(t-1) -> B-fragment (in-lane, k-permutation on Wh side)
    bf16x8 hh, hl;
    split_pack8(hD[0], hD[1], hh, hl);

    // 2. rec MFMAs chain onto the precomputed xp accumulators (3-deep chains)
    f32x4 az[2], ar[2], arh[2];
#pragma unroll
    for (int tl = 0; tl < 2; ++tl) {
      az[tl]  = MFMA(wh_hi[tl],     hh, xpC[tl]);
      az[tl]  = MFMA(wh_hi[tl],     hl, az[tl]);
      az[tl]  = MFMA(wh_lo[tl],     hh, az[tl]);
      ar[tl]  = MFMA(wh_hi[2 + tl], hh, xpC[2 + tl]);
      ar[tl]  = MFMA(wh_hi[2 + tl], hl, ar[tl]);
      ar[tl]  = MFMA(wh_lo[2 + tl], hh, ar[tl]);
      arh[tl] = MFMA(wh_hi[4 + tl], hh, bh2[tl]);
      arh[tl] = MFMA(wh_hi[4 + tl], hl, arh[tl]);
      arh[tl] = MFMA(wh_lo[4 + tl], hh, arh[tl]);
    }

    // 3. e(t+1) fragments + xp-ahead (independent; fills the gate-chain stall)
    bf16x8 ebh, ebl;
    if constexpr (TOWER == 1) {
      const int s = (t + 1 < SEQ_T) ? t + 1 : SEQ_T - 1;
      price_frag(s, ebh, ebl);
    } else {
      split_pack8(eNa, eNb, ebh, ebl);
    }
#pragma unroll
    for (int tl = 0; tl < 2; ++tl) {
      xpN[tl]     = MFMA(wx_hi[tl],     ebh, cz[tl]);
      xpN[tl]     = MFMA(wx_hi[tl],     ebl, xpN[tl]);
      xpN[tl]     = MFMA(wx_lo[tl],     ebh, xpN[tl]);
      xpN[2 + tl] = MFMA(wx_hi[2 + tl], ebh, cr[tl]);
      xpN[2 + tl] = MFMA(wx_hi[2 + tl], ebl, xpN[2 + tl]);
      xpN[2 + tl] = MFMA(wx_lo[2 + tl], ebh, xpN[2 + tl]);
      xpN[4 + tl] = MFMA(wx_hi[4 + tl], ebh, bi2[tl]);
      xpN[4 + tl] = MFMA(wx_hi[4 + tl], ebl, xpN[4 + tl]);
      xpN[4 + tl] = MFMA(wx_lo[4 + tl], ebh, xpN[4 + tl]);
    }

    // 4. prefetch e(t+2) (item/dept)
    if constexpr (TOWER != 1) {
      const int s = (t + 2 < SEQ_T) ? t + 2 : SEQ_T - 1;
      pf(s, eNa, eNb);
    }

    // 5. staging refill (once per 16 steps; double-buffered; no barrier)
    if ((t & 15) == 0 && t + 16 < SEQ_T) stage(t + 16, ((t >> 4) + 1) & 1);

    // 6. gates (batch = l15, hidden = tl*16 + quad*4 + rg); exp2-direct
    const bool mk = get_mask(t);
#pragma unroll
    for (int tl = 0; tl < 2; ++tl)
#pragma unroll
      for (int rg = 0; rg < 4; ++rg) {
        const float z  = rcp_fast(1.0f + EXP2F(-az[tl][rg]));
        const float r  = rcp_fast(1.0f + EXP2F(-ar[tl][rg]));
        const float e  = EXP2F(-(xpC[4 + tl][rg] + r * arh[tl][rg]));
        const float g  = (1.0f - e) * rcp_fast(1.0f + e);
        const float hn = g + z * (hD[tl][rg] - g);    // = z*h + (1-z)*g
        if constexpr (TOWER == 0) hD[tl][rg] = hn;
        else                      hD[tl][rg] = mk ? hn : hD[tl][rg];
      }
  };

  for (int t = 0; t < SEQ_T; t += 2) {                // ping-pong: no rotation movs
    step(t,     xpA, xpB);
    step(t + 1, xpB, xpA);
  }

#pragma unroll
  for (int tl = 0; tl < 2; ++tl)
    *(f32x4*)(out + (size_t)bRow * H3 + TOWER * ED + tl * 16 + quad * 4) = hD[tl];
}

__global__ void __launch_bounds__(64, 1) gru_fused(
    const int* __restrict__ ids, const float* __restrict__ prices, const int* __restrict__ depts,
    const float* __restrict__ item_table, const float* __restrict__ price_table,
    const float* __restrict__ dept_table,
    const float* __restrict__ item_Wx, const float* __restrict__ item_Wh,
    const float* __restrict__ item_b,
    const float* __restrict__ price_Wx, const float* __restrict__ price_Wh,
    const float* __restrict__ price_b,
    const float* __restrict__ dept_Wx, const float* __restrict__ dept_Wh,
    const float* __restrict__ dept_b,
    const float* __restrict__ price_mean, const float* __restrict__ price_var,
    float* __restrict__ out) {
  __shared__ int sid[2][16][20];   // double-buffered 16-step id/price/dept stage
  const int tower = blockIdx.y;
  if (tower == 0) {
    tower_fused<0>(ids, prices, depts, item_table, item_Wx, item_Wh, item_b,
                   0.0f, 0.0f, out, sid);
  } else if (tower == 1) {
    const float pm = price_mean[0];
    const float pr = rsqrtf(price_var[0]);
    tower_fused<1>(ids, prices, depts, price_table, price_Wx, price_Wh, price_b,
                   pm, pr, out, sid);
  } else {
    tower_fused<2>(ids, prices, depts, dept_table, dept_Wx, dept_Wh, dept_b,
                   0.0f, 0.0f, out, sid);
  }
}

extern "C" void kernel_launch(void* const* d_in, const int* in_sizes, int n_in,
                              void* d_out, int out_size, void* d_ws, size_t ws_size,
                              hipStream_t stream) {
  const int*   ids         = (const int*)d_in[0];
  const float* prices      = (const float*)d_in[1];
  const int*   depts       = (const int*)d_in[2];
  const float* item_table  = (const float*)d_in[3];
  const float* price_table = (const float*)d_in[4];
  const float* dept_table  = (const float*)d_in[5];
  const float* item_Wx     = (const float*)d_in[6];
  const float* item_Wh     = (const float*)d_in[7];
  const float* item_b      = (const float*)d_in[8];
  const float* price_Wx    = (const float*)d_in[9];
  const float* price_Wh    = (const float*)d_in[10];
  const float* price_b     = (const float*)d_in[11];
  const float* dept_Wx     = (const float*)d_in[12];
  const float* dept_Wh     = (const float*)d_in[13];
  const float* dept_b      = (const float*)d_in[14];
  const float* price_mean  = (const float*)d_in[15];
  const float* price_var   = (const float*)d_in[16];
  float* out = (float*)d_out;

  dim3 grid(NB / 16, 3, 1);   // one wave per block; 768 single-wave blocks
  gru_fused<<<grid, 64, 0, stream>>>(
      ids, prices, depts, item_table, price_table, dept_table,
      item_Wx, item_Wh, item_b, price_Wx, price_Wh, price_b,
      dept_Wx, dept_Wh, dept_b, price_mean, price_var, out);
}